// Round 6
// baseline (839.457 us; speedup 1.0000x reference)
//
#include <hip/hip_runtime.h>

typedef __bf16 bf16_t;
typedef bf16_t bf16x8 __attribute__((ext_vector_type(8)));
typedef float f32x4 __attribute__((ext_vector_type(4)));
typedef unsigned short u16;

#define P_TOTAL 98304
#define PTS_PER_BATCH 49152

__device__ __forceinline__ u16 f2bs(float f){ bf16_t b=(bf16_t)f; return __builtin_bit_cast(u16,b); }

// lgkm-only barrier: preserves all LDS hazards but does NOT drain vmcnt ->
// cross-phase weight prefetch stays in flight.
__device__ __forceinline__ void bar_lds(){
  asm volatile("s_waitcnt lgkmcnt(0)" ::: "memory");
  __builtin_amdgcn_s_barrier();
  __builtin_amdgcn_sched_barrier(0);
}

// ---------- weight transform: (K=512,N=512) fp32 -> MFMA-fragment-linear bf16 ----------
// idx = ((nstrip*16 + kt)*2 + nt)*512 + lane*8 + j
//   value = W[k][n],  n = nstrip*32 + nt*16 + (lane&15),  k = kt*32 + (lane>>4)*8 + j
__global__ void k_wtrans15(const float* __restrict__ lz, const float* __restrict__ f0,
                           const float* __restrict__ f1, u16* __restrict__ dst){
  int kt = blockIdx.x, ns = blockIdx.y, z = blockIdx.z;
  const float* src = (z<5) ? (lz + (size_t)z*262144)
                   : (z<10 ? (f0 + (size_t)(z-5)*262144)
                           : (f1 + (size_t)(z-10)*262144));
  u16* d = dst + (size_t)z*262144 + (size_t)(ns*16 + kt)*1024;
  int l = threadIdx.x;
  int col = ns*32 + (l&15);
  int kr  = kt*32 + (l>>4)*8;
  #pragma unroll
  for (int nt=0;nt<2;nt++){
    bf16x8 o;
    #pragma unroll
    for (int j=0;j<8;j++) o[j] = (bf16_t)src[(size_t)(kr+j)*512 + col + nt*16];
    *(bf16x8*)(d + nt*512 + l*8) = o;
  }
}

// lin_in: (63,512) fp32 -> fragment-linear bf16, K padded to 64 (2 kt chunks)
__global__ void k_wtrans_in(const float* __restrict__ w, u16* __restrict__ dst){
  int kt = blockIdx.x, ns = blockIdx.y;
  u16* d = dst + (size_t)(ns*2 + kt)*1024;
  int l = threadIdx.x;
  int col = ns*32 + (l&15);
  int kr  = kt*32 + (l>>4)*8;
  #pragma unroll
  for (int nt=0;nt<2;nt++){
    bf16x8 o;
    #pragma unroll
    for (int j=0;j<8;j++){
      int k = kr + j;
      o[j] = (k < 63) ? (bf16_t)w[(size_t)k*512 + col + nt*16] : (bf16_t)0.f;
    }
    *(bf16x8*)(d + nt*512 + l*8) = o;
  }
}

// ---------- feature transpose: (B,512,128,128) f32 -> (B,128,128,512) bf16 ----------
__global__ void k_featT(const float* __restrict__ feat, u16* __restrict__ featT){
  int x = threadIdx.x;
  int c8 = blockIdx.x*8;
  int y = blockIdx.y, b = blockIdx.z;
  float v[8];
  #pragma unroll
  for (int j=0;j<8;j++)
    v[j] = feat[(((size_t)(b*512 + c8 + j))*128 + y)*128 + x];
  bf16x8 o;
  #pragma unroll
  for (int j=0;j<8;j++) o[j] = (bf16_t)v[j];
  *(bf16x8*)(featT + (((size_t)(b*128 + y))*128 + x)*512 + c8) = o;
}

// ---------- per-point: geometry + bilinear + positional encoding ----------
// 16 points per block (16 waves). Outputs are written FRAGMENT-LINEAR so k_net
// staging is a straight linear copy:
//   alignedF idx = (p>>6)*32768 + (kt*4 + ((p>>4)&3))*512 + (fk8*16 + (p&15))*8 + j
//     value = act[p][k = kt*32 + fk8*8 + j]
//   encF    idx = (p>>6)*4096  + (kt*4 + ((p>>4)&3))*512 + (fk8*16 + (p&15))*8 + j  (kt<2)
__global__ __launch_bounds__(1024) void k_points(
    const float* __restrict__ world, const float* __restrict__ c2w,
    const float* __restrict__ kmat, const u16* __restrict__ featT,
    u16* __restrict__ alignedF, u16* __restrict__ encF){
  __shared__ u16 act[16*520];   // [16 pts][512 ch], pad 8 -> conflict-free both phases
  __shared__ u16 encs[16*72];   // [16 pts][64 k], pad 8
  int wid = threadIdx.x >> 6, lane = threadIdx.x & 63;
  int p0 = blockIdx.x*16;
  int gp = p0 + wid;
  int b = gp / PTS_PER_BATCH;
  const float* wp = world + (size_t)gp*3;
  float px = wp[0], py = wp[1], pz = wp[2];
  const float* cw = c2w + b*16;
  float dx = px - cw[3], dy = py - cw[7], dz = pz - cw[11];
  float cx = cw[0]*dx + cw[4]*dy + cw[8]*dz;
  float cy = cw[1]*dx + cw[5]*dy + cw[9]*dz;
  float cz = cw[2]*dx + cw[6]*dy + cw[10]*dz;
  const float* km = kmat + b*9;
  float u0 = km[0]*cx + km[1]*cy + km[2]*cz;
  float v0 = km[3]*cx + km[4]*cy + km[5]*cz;
  float zz = km[6]*cx + km[7]*cy + km[8]*cz;
  if (fabsf(zz) < 1e-6f) zz = 1e-6f;
  float uu = u0/zz, vv = v0/zz;
  float xf = fminf(fmaxf(uu, 0.f), 127.f);
  float yf = fminf(fmaxf(vv, 0.f), 127.f);
  float x0f = floorf(xf), y0f = floorf(yf);
  int x0 = (int)x0f, y0 = (int)y0f;
  int x1 = min(x0+1,127), y1 = min(y0+1,127);
  float wx = xf - x0f, wy = yf - y0f;
  float w00 = (1.f-wx)*(1.f-wy), w01 = wx*(1.f-wy), w10 = (1.f-wx)*wy, w11 = wx*wy;
  size_t fb = (size_t)b*128*128*512;
  int c8 = lane*8;
  const bf16x8 t00 = *(const bf16x8*)(featT + fb + (size_t)(y0*128+x0)*512 + c8);
  const bf16x8 t01 = *(const bf16x8*)(featT + fb + (size_t)(y0*128+x1)*512 + c8);
  const bf16x8 t10 = *(const bf16x8*)(featT + fb + (size_t)(y1*128+x0)*512 + c8);
  const bf16x8 t11 = *(const bf16x8*)(featT + fb + (size_t)(y1*128+x1)*512 + c8);
  bf16x8 o;
  #pragma unroll
  for (int j=0;j<8;j++){
    float r = (float)t00[j]*w00 + (float)t01[j]*w01 + (float)t10[j]*w10 + (float)t11[j]*w11;
    o[j] = (bf16_t)r;
  }
  *(bf16x8*)&act[wid*520 + lane*8] = o;
  float cam[3] = {cx, cy, cz};
  float e;
  if (lane < 3) e = cam[lane];
  else if (lane < 33){
    int i = (lane-3)/10, f = (lane-3)%10;
    e = sinf(6.2831855f * cam[i] * (float)(1<<f));
  } else if (lane < 63){
    int i = (lane-33)/10, f = (lane-33)%10;
    e = cosf(6.2831855f * cam[i] * (float)(1<<f));
  } else e = 0.f;
  encs[wid*72 + lane] = f2bs(e);
  __syncthreads();
  // fragment-linear output (coalesced 1 KB per wave)
  int t = threadIdx.x;
  int g = blockIdx.x & 3;
  size_t blk = (size_t)(blockIdx.x >> 2);
  {
    int kt = t>>6, lo = t&63, fm = lo&15, fk8 = lo>>4;
    bf16x8 v = *(const bf16x8*)&act[fm*520 + kt*32 + fk8*8];
    *(bf16x8*)(alignedF + blk*32768 + (size_t)(kt*4+g)*512 + lo*8) = v;
  }
  if (t < 128){
    int kt = t>>6, lo = t&63, fm = lo&15, fk8 = lo>>4;
    bf16x8 v = *(const bf16x8*)&encs[fm*72 + kt*32 + fk8*8];
    *(bf16x8*)(encF + blk*4096 + (size_t)(kt*4+g)*512 + lo*8) = v;
  }
}

// ============ fused persistent MLP: 512 thr (8 waves), M=64/block ============
// LDS activations stored FRAGMENT-LINEAR [kt][m-group bt][512]:
//   - every B-read is a contiguous 1 KB wave ds_read_b128 -> zero bank conflict,
//     all 64 reads of a gemm fold to immediate offsets off ONE base.
//   - write_relu: 16 ds_write_b64 off one thread base, all-immediate, bank-balanced.
//   - no a[d] register copies: MFMAs consume a[d], THEN slot reloads kt+2 (WAR).
// Weights = A-operand (fragment-linear 1KB global wave-loads, L2-served).
// C[n][m]: lane holds m = bt*16+(l&15); reg r holds n = w*64+nt*16+(l>>4)*4+r.

#define MFMA_BF16 __builtin_amdgcn_mfma_f32_16x16x32_bf16

template<int NK>
__device__ __forceinline__ void gemm3(const u16* sB, const u16* __restrict__ apS,
                                      const u16* __restrict__ apN,
                                      int l, f32x4 (&acc)[4][4], bf16x8 (&a)[2][4]){
  const u16* bp = sB + l*8;
  bf16x8 br[2][4];
  #pragma unroll
  for (int bt=0; bt<4; ++bt) br[0][bt] = *(const bf16x8*)(bp + bt*512);
  #pragma unroll 1
  for (int kb=0; kb<NK/2-1; ++kb){
    #pragma unroll
    for (int d=0; d<2; ++d){
      const int kt = kb*2 + d;
      // prefetch B for kt+1 (opposite parity slot)
      #pragma unroll
      for (int bt=0; bt<4; ++bt)
        br[d^1][bt] = *(const bf16x8*)(bp + (kt+1)*2048 + bt*512);
      #pragma unroll
      for (int bt=0; bt<4; ++bt){
        acc[bt][0] = MFMA_BF16(a[d][0], br[d][bt], acc[bt][0], 0,0,0);
        acc[bt][1] = MFMA_BF16(a[d][1], br[d][bt], acc[bt][1], 0,0,0);
        acc[bt][2] = MFMA_BF16(a[d][2], br[d][bt], acc[bt][2], 0,0,0);
        acc[bt][3] = MFMA_BF16(a[d][3], br[d][bt], acc[bt][3], 0,0,0);
      }
      // reload slot d with kt+2 A-fragments (consumed 2 iters later)
      #pragma unroll
      for (int nt=0; nt<4; ++nt)
        a[d][nt] = *(const bf16x8*)(apS + (nt>>1)*(NK*1024) + (kt+2)*1024 + (nt&1)*512);
    }
  }
  // tail: kt = NK-2, NK-1; A-prefetch targets the NEXT phase (NK'=16 layout)
  #pragma unroll
  for (int d=0; d<2; ++d){
    if (d == 0){
      #pragma unroll
      for (int bt=0; bt<4; ++bt)
        br[1][bt] = *(const bf16x8*)(bp + (NK-1)*2048 + bt*512);
    }
    #pragma unroll
    for (int bt=0; bt<4; ++bt){
      acc[bt][0] = MFMA_BF16(a[d][0], br[d][bt], acc[bt][0], 0,0,0);
      acc[bt][1] = MFMA_BF16(a[d][1], br[d][bt], acc[bt][1], 0,0,0);
      acc[bt][2] = MFMA_BF16(a[d][2], br[d][bt], acc[bt][2], 0,0,0);
      acc[bt][3] = MFMA_BF16(a[d][3], br[d][bt], acc[bt][3], 0,0,0);
    }
    #pragma unroll
    for (int nt=0; nt<4; ++nt)
      a[d][nt] = *(const bf16x8*)(apN + (nt>>1)*16384 + d*1024 + (nt&1)*512);
  }
}

__device__ __forceinline__ void add_bias2(const float* __restrict__ bias, int wn64, int rq,
                                          f32x4 (&acc)[4][4]){
  #pragma unroll
  for (int nt=0; nt<4; ++nt){
    f32x4 bv = *(const f32x4*)&bias[wn64 + nt*16 + rq];
    #pragma unroll
    for (int bt=0; bt<4; ++bt)
      #pragma unroll
      for (int r=0; r<4; ++r)
        acc[bt][nt][r] += bv[r];
  }
}

// write relu(acc) bf16 into fragment-linear bufB; all offsets immediate.
// k = w*64 + nt*16 + fk8*4 + r -> kt = w*2+(nt>>1), lane' = ((fk8>>1)+2*(nt&1))*16+fm,
// j = (fk8&1)*4+r.  u16 idx = kt*2048 + bt*512 + lane'*8 + (fk8&1)*4.
__device__ __forceinline__ void write_relu3(u16* dst, int w, int fm, int fk8,
                                            f32x4 (&acc)[4][4]){
  u16* base = dst + w*4096 + (fk8>>1)*128 + fm*8 + (fk8&1)*4;
  #pragma unroll
  for (int bt=0; bt<4; ++bt)
    #pragma unroll
    for (int nt=0; nt<4; ++nt){
      u16 p0 = f2bs(fmaxf(acc[bt][nt][0], 0.f));
      u16 p1 = f2bs(fmaxf(acc[bt][nt][1], 0.f));
      u16 p2 = f2bs(fmaxf(acc[bt][nt][2], 0.f));
      u16 p3 = f2bs(fmaxf(acc[bt][nt][3], 0.f));
      uint2 v;
      v.x = (unsigned)p0 | ((unsigned)p1 << 16);
      v.y = (unsigned)p2 | ((unsigned)p3 << 16);
      *(uint2*)(base + (nt>>1)*2048 + (nt&1)*256 + bt*512) = v;
    }
}

__global__ __launch_bounds__(512, 2) void k_net(
    const u16* __restrict__ alignedF, const u16* __restrict__ encF,
    const u16* __restrict__ wtin, const float* __restrict__ b_in,
    const u16* __restrict__ wts, const float* __restrict__ bz,
    const float* __restrict__ b0, const float* __restrict__ b1,
    const float* __restrict__ wout, const float* __restrict__ bout,
    float* __restrict__ out)
{
  __shared__ u16 bufA[32768];   // aligned, fragment-linear (64 KB, persistent)
  __shared__ u16 bufB[32768];   // activations, fragment-linear (64 KB)
  const int t = threadIdx.x, w = t>>6, l = t&63;
  const int wn64 = w*64, fm = l&15, fk8 = l>>4, rq = (l>>4)*4;

  // staging reads (issue first so their vmcnt drain doesn't cover afr loads)
  uint4 sa[8];
  const uint4* srcA = (const uint4*)(alignedF + (size_t)blockIdx.x*32768);
  #pragma unroll
  for (int j=0;j<8;j++) sa[j] = srcA[j*512 + t];
  uint4 sb = *((const uint4*)(encF + (size_t)blockIdx.x*4096) + t);

  // preload A-fragments for the enc-gemm (stays in flight through staging)
  const u16* apE = wtin + (size_t)w*4096 + l*8;
  bf16x8 afr[2][4];
  #pragma unroll
  for (int d=0; d<2; ++d)
    #pragma unroll
    for (int nt=0; nt<4; ++nt)
      afr[d][nt] = *(const bf16x8*)(apE + (nt>>1)*2048 + d*1024 + (nt&1)*512);

  // linear LDS fill (fragment-linear layouts match global exactly)
  #pragma unroll
  for (int j=0;j<8;j++) *((uint4*)bufA + j*512 + t) = sa[j];
  *((uint4*)bufB + t) = sb;
  bar_lds();

  const u16* apz0 = wts + (size_t)w*32768 + l*8;
  f32x4 h[4][4] = {};
  gemm3<2>(bufB, apE, apz0, l, h, afr);
  add_bias2(b_in, wn64, rq, h);

  #pragma unroll 1
  for (int i=0;i<5;i++){
    const u16* apz  = wts + (size_t)i*262144      + (size_t)w*32768 + l*8;
    const u16* apf0 = wts + (size_t)(5+i)*262144  + (size_t)w*32768 + l*8;
    const u16* apf1 = wts + (size_t)(10+i)*262144 + (size_t)w*32768 + l*8;
    const u16* apzn = (i<4) ? (wts + (size_t)(i+1)*262144 + (size_t)w*32768 + l*8) : apE;

    gemm3<16>(bufA, apz, apf0, l, h, afr);       // h += aligned @ Wz
    add_bias2(bz + i*512, wn64, rq, h);
    bar_lds();                                   // prior bufB readers done
    write_relu3(bufB, w, fm, fk8, h);            // bufB = relu(h)
    bar_lds();
    f32x4 acc[4][4] = {};
    gemm3<16>(bufB, apf0, apf1, l, acc, afr);    // net = relu(h) @ W0
    add_bias2(b0 + i*512, wn64, rq, acc);
    bar_lds();                                   // all fc0 reads of bufB done
    write_relu3(bufB, w, fm, fk8, acc);          // bufB = relu(net)
    bar_lds();
    gemm3<16>(bufB, apf1, apzn, l, h, afr);      // h += relu(net) @ W1
    add_bias2(b1 + i*512, wn64, rq, h);
  }

  // sigma = exp(relu(h) . wout + bout); per lane: 4 m-cols (bt), 16 n-rows (nt,r)
  float s[4];
  {
    #pragma unroll
    for (int bt=0; bt<4; ++bt) s[bt] = 0.f;
    #pragma unroll
    for (int nt=0; nt<4; ++nt){
      f32x4 wv = *(const f32x4*)&wout[wn64 + nt*16 + rq];
      #pragma unroll
      for (int bt=0; bt<4; ++bt)
        #pragma unroll
        for (int r=0; r<4; ++r)
          s[bt] += fmaxf(h[bt][nt][r], 0.f) * wv[r];
    }
  }
  #pragma unroll
  for (int bt=0; bt<4; ++bt){
    s[bt] += __shfl_xor(s[bt], 16, 64);    // fold the 4 (l>>4) rq-groups
    s[bt] += __shfl_xor(s[bt], 32, 64);
  }
  bar_lds();                       // all fc1 reads of bufB done; reuse as red[8][64]
  float* red = (float*)bufB;
  if (l < 16){
    #pragma unroll
    for (int bt=0; bt<4; ++bt)
      red[w*64 + bt*16 + l] = s[bt];
  }
  bar_lds();
  if (t < 64){
    float a = bout[0];
    #pragma unroll
    for (int wv=0; wv<8; wv++) a += red[wv*64 + t];
    out[blockIdx.x*64 + t] = expf(a);
  }
}

extern "C" void kernel_launch(void* const* d_in, const int* in_sizes, int n_in,
                              void* d_out, int out_size, void* d_ws, size_t ws_size,
                              hipStream_t stream) {
  const float* world = (const float*)d_in[0];
  const float* c2w   = (const float*)d_in[1];
  const float* kmat  = (const float*)d_in[2];
  const float* feat  = (const float*)d_in[3];
  const float* w_in  = (const float*)d_in[4];
  const float* b_in  = (const float*)d_in[5];
  const float* w_z   = (const float*)d_in[6];
  const float* b_z   = (const float*)d_in[7];
  const float* w_f0  = (const float*)d_in[8];
  const float* b_f0  = (const float*)d_in[9];
  const float* w_f1  = (const float*)d_in[10];
  const float* b_f1  = (const float*)d_in[11];
  const float* w_out = (const float*)d_in[12];
  const float* b_out = (const float*)d_in[13];
  float* out = (float*)d_out;
  char* ws = (char*)d_ws;

  size_t off = 0;
  u16* wts   = (u16*)(ws + off); off += (size_t)15*262144*2;       // 15x fragment-linear bf16
  u16* wtin  = (u16*)(ws + off); off += (size_t)512*64*2;          // lin_in fragment-linear bf16
  u16* featT = (u16*)(ws + off); off += (size_t)2*128*128*512*2;   // transposed features
  u16* alignedF = (u16*)(ws + off); off += (size_t)P_TOTAL*512*2;  // sampled feats, frag-linear
  u16* encF  = (u16*)(ws + off); off += (size_t)P_TOTAL*64*2;      // pos-enc, frag-linear

  k_wtrans15<<<dim3(16,16,15), 64, 0, stream>>>(w_z, w_f0, w_f1, wts);
  k_wtrans_in<<<dim3(2,16,1), 64, 0, stream>>>(w_in, wtin);
  k_featT<<<dim3(64,128,2), 128, 0, stream>>>(feat, featT);
  k_points<<<dim3(P_TOTAL/16), 1024, 0, stream>>>(world, c2w, kmat, featT, alignedF, encF);
  k_net<<<dim3(P_TOTAL/64), 512, 0, stream>>>(alignedF, encF, wtin, b_in, wts,
      b_z, b_f0, b_f1, w_out, b_out, out);
}